// Round 9
// baseline (2636.021 us; speedup 1.0000x reference)
//
#include <hip/hip_runtime.h>
#include <stdint.h>

#define NND 50000
#define NNDP 50016            // table row-stride (sentinel zero row at index NND)
#define NE  1600000
#define INC 129
#define TP  25
#define NTR 25000
#define MPAD 50048
#define NB_SCAN 196           // ceil(50000/256)
#define CSR_MAX (NE + 8*NND + 128)

typedef short bf16x8 __attribute__((ext_vector_type(8)));
typedef float f32x4 __attribute__((ext_vector_type(4)));
typedef float f32x2 __attribute__((ext_vector_type(2)));
typedef uint32_t u32x4 __attribute__((ext_vector_type(4)));

__device__ __forceinline__ uint32_t f2bf(float f){
  union{float ff; uint32_t u;} v; v.ff=f;
  return (v.u + 0x7FFFu + ((v.u>>16)&1u))>>16;
}
__device__ __forceinline__ uint32_t pack2(float a, float b){
  return f2bf(a) | (f2bf(b)<<16);
}
__device__ __forceinline__ float sigm(float v){ return 1.f/(1.f+__expf(-v)); }

// -------- weight prep: Weff = W_g @ Wl_g[:64] (+bias row at K=129), stored as
// TRANSPOSED A-fragments: frag (g,kk,rt), lane=(kgrp,c16): row j = g*64+rt*16+c16,
// k = kk*32 + kgrp*8 + e (e=0..7), dword e>>1, half e&1. Wlf: same for Wl_h[64:].
__global__ void k_prep(const float* Wz, const float* bz, const float* Wlz, const float* blz,
                       const float* Wr, const float* br, const float* Wlr, const float* blr,
                       const float* Wh, const float* bh, const float* Wlh, const float* blh,
                       uint16_t* WfT, uint16_t* Wlf)
{
  int idx = blockIdx.x*256 + threadIdx.x;
  if (idx < 192*224) {
    int j = idx / 224, k = idx - j*224;
    int g = j >> 6, jj = j & 63;
    const float* W  = g==0?Wz :(g==1?Wr :Wh);
    const float* Wl = g==0?Wlz:(g==1?Wlr:Wlh);
    const float* b  = g==0?bz :(g==1?br :bh);
    const float* bl = g==0?blz:(g==1?blr:blh);
    float v = 0.f;
    if (k < INC) {
      for (int m=0;m<64;m++) v += W[k*64+m]*Wl[m*64+jj];
    } else if (k == 129) {                       // bias row (AX ch129 == 1.0)
      v = bl[jj];
      for (int m=0;m<64;m++) v += b[m]*Wl[m*64+jj];
    } else if (k >= 160) {
      v = (g<2) ? Wl[(64+(k-160))*64 + jj] : 0.f;
    }
    int rt = jj>>4, c16 = jj&15;
    int kk = k>>5, kgrp = (k>>3)&3, e = k&7;
    int lane = kgrp*16 + c16;
    WfT[((((g*7+kk)*4+rt)*256 + lane*4 + (e>>1))<<1) + (e&1)] = (uint16_t)f2bf(v);
  } else if (idx < 192*224 + 4096) {
    int t2 = idx - 192*224; int j2 = t2>>6, k2 = t2&63;
    float v = Wlh[(64+k2)*64 + j2];
    int rt = j2>>4, c16 = j2&15;
    int kk2 = k2>>5, kgrp = (k2>>3)&3, e = k2&7;
    int lane = kgrp*16 + c16;
    Wlf[(((kk2*4+rt)*256 + lane*4 + (e>>1))<<1) + (e&1)] = (uint16_t)f2bf(v);
  }
}

__global__ void k_probs(const float* att, float* probs){
  if (threadIdx.x==0 && blockIdx.x==0){
    float m=-1e30f;
    for (int i=0;i<TP;i++) m = fmaxf(m, att[i]);
    float e[TP]; float s=0.f;
    for (int i=0;i<TP;i++){ e[i]=__expf(att[i]-m); s+=e[i]; }
    for (int i=0;i<TP;i++) probs[i]=e[i]/s;
  }
}

__global__ void k_hist(const int* eidx, int* deg){
  int e = blockIdx.x*256 + threadIdx.x;
  if (e < NE) atomicAdd(&deg[eidx[NE + e]], 1);   // dst row
}

__global__ void k_dinv(const int* deg, float* dinv){
  int n = blockIdx.x*256 + threadIdx.x;
  if (n < NND) dinv[n] = rsqrtf(1.0f + (float)deg[n]);
}

// ---- scan of padded row sizes p_i = (deg_i+1 rounded up to mult of 8) ----
__global__ void k_scan1(const int* deg, int* row_ptr, int* bsum){
  __shared__ int s[256];
  int tid = threadIdx.x;
  int i = blockIdx.x*256 + tid;
  int v = (i < NND) ? ((deg[i]+8)&~7) : 0;
  s[tid] = v; __syncthreads();
  for (int d=1; d<256; d<<=1){
    int t = (tid>=d) ? s[tid-d] : 0;
    __syncthreads();
    s[tid] += t; __syncthreads();
  }
  if (i < NND) row_ptr[i] = s[tid] - v;
  if (tid == 255) bsum[blockIdx.x] = s[255];
}
__global__ void k_scan2(int* bsum, int* boff, int* row_ptr){
  __shared__ int s[256];
  int tid = threadIdx.x;
  int v = (tid < NB_SCAN) ? bsum[tid] : 0;
  s[tid] = v; __syncthreads();
  for (int d=1; d<256; d<<=1){
    int t = (tid>=d) ? s[tid-d] : 0;
    __syncthreads();
    s[tid] += t; __syncthreads();
  }
  if (tid < NB_SCAN) boff[tid] = s[tid] - v;
  if (tid == NB_SCAN-1) row_ptr[NND] = s[tid];
}
__global__ void k_scan3(int* row_ptr, const int* boff){
  int i = blockIdx.x*256 + threadIdx.x;
  if (i < NND) row_ptr[i] += boff[blockIdx.x];
}

__global__ void k_fill(const int* eidx, const int* rp, int* cnt, uint16_t* csr){
  int e = blockIdx.x*256 + threadIdx.x;
  if (e < NE){
    int s = eidx[e], d = eidx[NE+e];
    int pos = rp[d] + atomicAdd(&cnt[d],1);
    csr[pos] = (uint16_t)s;
  }
}
// self-loop entry + sentinel padding (src=NND -> zero table row)
__global__ void k_self(const int* rp, const int* deg, uint16_t* csr){
  int n = blockIdx.x*256 + threadIdx.x;
  if (n < NND){
    int base = rp[n] + deg[n];
    int endp = rp[n+1];
    csr[base] = (uint16_t)n;
    for (int j=base+1; j<endp; j++) csr[j] = (uint16_t)NND;
  }
}

// x (N,129,25) fp32 -> tables pre-scaled by dinv[n]:
//   xT8[t][n][32 uints]  (ch 0..127 as fp8 e4m3, 128B rows = 1 cache line)
//   xsl[t][n] f32        (ch 128, exact)
__global__ __launch_bounds__(256) void k_transpose3(const float* __restrict__ x,
                                                    const float* __restrict__ dinv,
                                                    uint32_t* __restrict__ xT8,
                                                    float* __restrict__ xsl){
  __shared__ float lx[3232];           // 129*25 = 3225
  int n = blockIdx.x;
  const float* xr = x + (size_t)n*(INC*TP);
  for (int e=threadIdx.x; e<INC*TP; e+=256) lx[e] = xr[e];
  __syncthreads();
  float dv = dinv[n];
  for (int idx=threadIdx.x; idx<TP*32; idx+=256){
    int t = idx>>5, u = idx&31;
    int c0 = u*4;
    float v0 = lx[(c0+0)*TP+t]*dv, v1 = lx[(c0+1)*TP+t]*dv;
    float v2 = lx[(c0+2)*TP+t]*dv, v3 = lx[(c0+3)*TP+t]*dv;
    int wlo = __builtin_amdgcn_cvt_pk_fp8_f32(v0, v1, 0, false);
    int w   = __builtin_amdgcn_cvt_pk_fp8_f32(v2, v3, wlo, true);
    xT8[((size_t)t*NNDP + n)*32 + u] = (uint32_t)w;
  }
  for (int t=threadIdx.x; t<TP; t+=256)
    xsl[(size_t)t*NNDP + n] = dv*lx[128*TP + t];
  if (blockIdx.x == 0){                // zero the sentinel rows
    for (int idx=threadIdx.x; idx<TP*32; idx+=256){
      int t = idx>>5, u = idx&31;
      xT8[((size_t)t*NNDP + NND)*32 + u] = 0u;
    }
    for (int t=threadIdx.x; t<TP; t+=256) xsl[(size_t)t*NNDP + NND] = 0.f;
  }
}

// Aggregation, scheme D + fp8: wave per (dst,t); edges serial; per edge ONE
// wave-uniform coalesced 128B row load, scalar CSR via s_load, HW fp8 decode.
__global__ __launch_bounds__(256) void k_agg(const uint16_t* __restrict__ xT8,
    const int* __restrict__ rp, const uint16_t* __restrict__ csr,
    const float* __restrict__ dinv, uint32_t* __restrict__ AX)
{
  int t = blockIdx.y;
  int wave = threadIdx.x>>6, lane = threadIdx.x&63;
  int d = blockIdx.x*4 + wave;
  int beg = __builtin_amdgcn_readfirstlane(rp[d]);
  int end = __builtin_amdgcn_readfirstlane(rp[d+1]);
  const uint16_t* tbl = xT8 + (size_t)t*((size_t)NNDP*64);   // 64 ushorts/row
  float a0=0.f, a1=0.f;
  for (int i0=beg; i0<end; i0+=8){
    ulonglong2 c = *(const ulonglong2*)(csr + i0);   // uniform -> s_load
    #pragma unroll
    for (int k=0;k<4;k++){
      int s0 = (int)((c.x >> (k*16)) & 0xFFFFu);     // scalar extracts
      int s1 = (int)((c.y >> (k*16)) & 0xFFFFu);
      uint32_t u0 = tbl[(size_t)s0*64 + lane];       // 128B row, 1 line
      uint32_t u1 = tbl[(size_t)s1*64 + lane];
      f32x2 v0 = __builtin_amdgcn_cvt_pk_f32_fp8((int)u0, false);
      f32x2 v1 = __builtin_amdgcn_cvt_pk_f32_fp8((int)u1, false);
      a0 += v0.x; a1 += v0.y;
      a0 += v1.x; a1 += v1.y;
    }
  }
  float dv = dinv[d];
  AX[(size_t)t*((size_t)MPAD*80) + (size_t)d*80 + lane] = pack2(dv*a0, dv*a1);
}

// channel 128 (+ bias channel 129 = 1.0): thread per (dst,t)
__global__ void k_aggL(const float* __restrict__ xsl,
    const int* __restrict__ rp, const uint16_t* __restrict__ csr,
    const float* __restrict__ dinv, uint32_t* __restrict__ AX)
{
  int t = blockIdx.y;
  int d = blockIdx.x*256 + threadIdx.x;
  if (d >= NND) return;
  const float* pl = xsl + (size_t)t*NNDP;
  float a = 0.f;
  int beg=rp[d], end=rp[d+1];
  #pragma unroll 4
  for (int i=beg;i<end;i++) a += pl[(int)csr[i]];
  AX[(size_t)t*((size_t)MPAD*80) + (size_t)d*80 + 64] = pack2(dinv[d]*a, 1.0f);
}

// Cross-lane rebuild: C-layout (lane=node holds ch rt*16+q*4+j) -> B-frag
// (lane=node holds 8 consecutive ch at q*8 within a 32-ch block).
// Pa*/Pb* = packed dword pairs of the two rt's of the chosen 32-ch half.
__device__ __forceinline__ u32x4 build_frag(uint32_t Pa0, uint32_t Pa1,
                                            uint32_t Pb0, uint32_t Pb1,
                                            int srcA, int srcB, bool rsel){
  uint32_t a0 = (uint32_t)__shfl((int)Pa0, srcA);
  uint32_t b0 = (uint32_t)__shfl((int)Pb0, srcA);
  uint32_t a1 = (uint32_t)__shfl((int)Pa1, srcA);
  uint32_t b1 = (uint32_t)__shfl((int)Pb1, srcA);
  uint32_t a2 = (uint32_t)__shfl((int)Pa0, srcB);
  uint32_t b2 = (uint32_t)__shfl((int)Pb0, srcB);
  uint32_t a3 = (uint32_t)__shfl((int)Pa1, srcB);
  uint32_t b3 = (uint32_t)__shfl((int)Pb1, srcB);
  u32x4 o;
  o.x = rsel?b0:a0; o.y = rsel?b1:a1; o.z = rsel?b2:a2; o.w = rsel?b3:a3;
  return o;
}

// Fused full recurrence, TRANSPOSED: one wave per 16 nodes, all 25 steps.
// D^T = mfma(A=weight-frag, B=activation-frag): C-output lane = node ->
// GRU update fully lane-local; H/HR live in registers; no LDS, no barriers.
__global__ __launch_bounds__(64, 3) void k_gru(const uint32_t* __restrict__ AX,
    const uint32_t* __restrict__ WfT, const uint32_t* __restrict__ Wlf,
    float* __restrict__ accum, const float* __restrict__ probs)
{
  int lane = threadIdx.x & 63;
  int c16 = lane & 15, q = lane >> 4;
  int node = blockIdx.x*16 + c16;
  bool rsel = (q & 2) != 0;
  int srcA = ((2*q)&3)*16 + c16;
  int srcB = ((2*q+1)&3)*16 + c16;

  f32x4 h[4] = {};                      // H[node][rt*16+q*4+j], f32 state
  f32x4 acr[4] = {};                    // attention accumulator
  u32x4 hf0 = {0,0,0,0}, hf1 = {0,0,0,0};  // H as bf16 B-frags (k 160..223)

  for (int t=0; t<TP; t++){
    const uint32_t* AXrow = AX + (size_t)t*((size_t)MPAD*80) + (size_t)node*80 + q*4;
    bf16x8 ax0 = *(const bf16x8*)(AXrow);
    bf16x8 ax1 = *(const bf16x8*)(AXrow+16);
    bf16x8 ax2 = *(const bf16x8*)(AXrow+32);
    bf16x8 ax3 = *(const bf16x8*)(AXrow+48);
    bf16x8 ax4 = *(const bf16x8*)(AXrow+64);

    f32x4 accg[3][4] = {};
    #pragma unroll
    for (int kk=0; kk<7; kk++){
      bf16x8 xv;
      if      (kk==0) xv = ax0;
      else if (kk==1) xv = ax1;
      else if (kk==2) xv = ax2;
      else if (kk==3) xv = ax3;
      else if (kk==4) xv = ax4;
      else if (kk==5) xv = __builtin_bit_cast(bf16x8, hf0);
      else            xv = __builtin_bit_cast(bf16x8, hf1);
      #pragma unroll
      for (int g=0; g<3; g++){
        if (g==2 && kk>=5) continue;       // zero weight block
        #pragma unroll
        for (int rt=0; rt<4; rt++){
          bf16x8 wv = *(const bf16x8*)(WfT + (((g*7+kk)*4+rt)<<8) + lane*4);
          accg[g][rt] = __builtin_amdgcn_mfma_f32_16x16x32_bf16(wv, xv, accg[g][rt],0,0,0);
        }
      }
    }

    // epilogue A: z (into accg[0]), r -> HR packed pairs (lane-local)
    uint32_t Phr[4][2];
    #pragma unroll
    for (int rt=0; rt<4; rt++){
      float hrv[4];
      #pragma unroll
      for (int j=0;j<4;j++){
        float z = sigm(accg[0][rt][j]);
        float r = sigm(accg[1][rt][j]);
        accg[0][rt][j] = z;
        hrv[j] = h[rt][j]*r;
      }
      Phr[rt][0] = pack2(hrv[0], hrv[1]);
      Phr[rt][1] = pack2(hrv[2], hrv[3]);
    }
    u32x4 hrf0 = build_frag(Phr[0][0],Phr[0][1],Phr[1][0],Phr[1][1], srcA,srcB,rsel);
    u32x4 hrf1 = build_frag(Phr[2][0],Phr[2][1],Phr[3][0],Phr[3][1], srcA,srcB,rsel);

    // GEMM2^T: Wl_h^T @ HR^T
    f32x4 acc2[4] = {};
    #pragma unroll
    for (int kk2=0; kk2<2; kk2++){
      bf16x8 bv = __builtin_bit_cast(bf16x8, kk2 ? hrf1 : hrf0);
      #pragma unroll
      for (int rt=0; rt<4; rt++){
        bf16x8 wv = *(const bf16x8*)(Wlf + ((kk2*4+rt)<<8) + lane*4);
        acc2[rt] = __builtin_amdgcn_mfma_f32_16x16x32_bf16(wv, bv, acc2[rt],0,0,0);
      }
    }

    // epilogue B: GRU update, attention accum, rebuild H frags
    float pt = probs[t];
    uint32_t Ph[4][2];
    #pragma unroll
    for (int rt=0; rt<4; rt++){
      #pragma unroll
      for (int j=0;j<4;j++){
        float ht = tanhf(acc2[rt][j] + accg[2][rt][j]);
        float z  = accg[0][rt][j];
        float hn = z*h[rt][j] + (1.f-z)*ht;
        h[rt][j] = hn;
        acr[rt][j] += pt*hn;
      }
      Ph[rt][0] = pack2(h[rt][0], h[rt][1]);
      Ph[rt][1] = pack2(h[rt][2], h[rt][3]);
    }
    hf0 = build_frag(Ph[0][0],Ph[0][1],Ph[1][0],Ph[1][1], srcA,srcB,rsel);
    hf1 = build_frag(Ph[2][0],Ph[2][1],Ph[3][0],Ph[3][1], srcA,srcB,rsel);
  }

  if (node < NND){
    #pragma unroll
    for (int rt=0; rt<4; rt++)
      *(f32x4*)&accum[(size_t)node*64 + rt*16 + q*4] = acr[rt];
  }
}

__global__ void k_out(const int* train_idx, const float* accum, const float* Wo,
                      const float* bo, const float* y, float* out){
  int i = blockIdx.x*256 + threadIdx.x;
  if (i < NTR){
    int n = train_idx[i];
    float s = bo[0];
    const float* ar = accum + (size_t)n*64;
    #pragma unroll
    for (int j=0;j<64;j++) s += ar[j]*Wo[j];
    out[i] = sigm(s);
    out[NTR+i] = y[n];
  }
}

extern "C" void kernel_launch(void* const* d_in, const int* in_sizes, int n_in,
                              void* d_out, int out_size, void* d_ws, size_t ws_size,
                              hipStream_t stream)
{
  const float* x   = (const float*)d_in[0];
  const int*   eix = (const int*)d_in[1];
  const float* y   = (const float*)d_in[2];
  const int*   tri = (const int*)d_in[3];
  const float* Wz  = (const float*)d_in[4];
  const float* bz  = (const float*)d_in[5];
  const float* Wlz = (const float*)d_in[6];
  const float* blz = (const float*)d_in[7];
  const float* Wr  = (const float*)d_in[8];
  const float* br  = (const float*)d_in[9];
  const float* Wlr = (const float*)d_in[10];
  const float* blr = (const float*)d_in[11];
  const float* Wh  = (const float*)d_in[12];
  const float* bh  = (const float*)d_in[13];
  const float* Wlh = (const float*)d_in[14];
  const float* blh = (const float*)d_in[15];
  const float* att = (const float*)d_in[16];
  const float* Wo  = (const float*)d_in[17];
  const float* bo  = (const float*)d_in[18];
  float* out = (float*)d_out;

  char* w = (char*)d_ws;
  size_t off = 0;
  auto alloc = [&](size_t sz)->size_t{ size_t o=off; off=(off+sz+255)&~(size_t)255; return o; };

  // --- zero block (one small memset) ---
  size_t zo = off;
  size_t o_deg   = alloc((size_t)NND*4);
  size_t o_cnt   = alloc((size_t)NND*4);
  size_t zlen = off - zo;
  // --- rest ---
  size_t o_dinv  = alloc((size_t)NND*4);
  size_t o_rp    = alloc((size_t)(NND+1)*4);
  size_t o_bsum  = alloc((size_t)NB_SCAN*4);
  size_t o_boff  = alloc((size_t)NB_SCAN*4);
  size_t o_csr   = alloc((size_t)CSR_MAX*2);
  size_t o_WfT   = alloc((size_t)84*512*2);       // 84 fragments x 1KB
  size_t o_Wlf   = alloc((size_t)8*512*2);
  size_t o_probs = alloc((size_t)TP*4);
  size_t o_accum = alloc((size_t)MPAD*64*4);
  size_t o_AX    = alloc((size_t)TP*MPAD*80*4);   // 400 MB, all t
  size_t o_xT8   = alloc((size_t)TP*NNDP*128);    // 160 MB (fp8 table)
  size_t o_xl    = alloc((size_t)TP*NNDP*4);      // 5 MB
  (void)ws_size; (void)in_sizes; (void)n_in; (void)out_size;

  int*      deg   = (int*)(w+o_deg);
  int*      cnt   = (int*)(w+o_cnt);
  float*    dinv  = (float*)(w+o_dinv);
  int*      rp    = (int*)(w+o_rp);
  int*      bsum  = (int*)(w+o_bsum);
  int*      boff  = (int*)(w+o_boff);
  uint16_t* csr   = (uint16_t*)(w+o_csr);
  uint16_t* WfT   = (uint16_t*)(w+o_WfT);
  uint16_t* Wlf   = (uint16_t*)(w+o_Wlf);
  float*    probs = (float*)(w+o_probs);
  float*    accum = (float*)(w+o_accum);
  uint32_t* AX    = (uint32_t*)(w+o_AX);
  uint32_t* xT8   = (uint32_t*)(w+o_xT8);
  float*    xsl   = (float*)(w+o_xl);

  hipMemsetAsync(w+zo, 0, zlen, stream);

  k_prep<<<(192*224 + 4096 + 255)/256, 256, 0, stream>>>(
      Wz,bz,Wlz,blz, Wr,br,Wlr,blr, Wh,bh,Wlh,blh, WfT, Wlf);
  k_probs<<<1, 64, 0, stream>>>(att, probs);
  k_hist<<<(NE+255)/256, 256, 0, stream>>>(eix, deg);
  k_dinv<<<(NND+255)/256, 256, 0, stream>>>(deg, dinv);
  k_scan1<<<NB_SCAN, 256, 0, stream>>>(deg, rp, bsum);
  k_scan2<<<1, 256, 0, stream>>>(bsum, boff, rp);
  k_scan3<<<NB_SCAN, 256, 0, stream>>>(rp, boff);
  k_fill<<<(NE+255)/256, 256, 0, stream>>>(eix, rp, cnt, csr);
  k_self<<<NB_SCAN, 256, 0, stream>>>(rp, deg, csr);
  k_transpose3<<<NND, 256, 0, stream>>>(x, dinv, xT8, xsl);

  k_agg <<<dim3(12500, TP), 256, 0, stream>>>((const uint16_t*)xT8, rp, csr, dinv, AX);
  k_aggL<<<dim3(NB_SCAN, TP), 256, 0, stream>>>(xsl, rp, csr, dinv, AX);

  k_gru<<<MPAD/16, 64, 0, stream>>>(AX, (const uint32_t*)WfT,
                                    (const uint32_t*)Wlf, accum, probs);
  k_out<<<(NTR+255)/256, 256, 0, stream>>>(tri, accum, Wo, bo, y, out);
}

// Round 10
// 2258.095 us; speedup vs baseline: 1.1674x; 1.1674x over previous
//
#include <hip/hip_runtime.h>
#include <stdint.h>

#define NND 50000
#define NNDP 50016            // table row-stride (sentinel zero row at index NND)
#define NE  1600000
#define INC 129
#define TP  25
#define NTR 25000
#define MPAD 50048
#define NB_SCAN 196           // ceil(50000/256)
#define CSR_MAX (NE + 8*NND + 128)
#define NFRAG 92              // 84 gate fragments + 8 Wl_h fragments
#define WLDS_BYTES (NFRAG*1024)

typedef short bf16x8 __attribute__((ext_vector_type(8)));
typedef float f32x4 __attribute__((ext_vector_type(4)));
typedef float f32x2 __attribute__((ext_vector_type(2)));
typedef uint32_t u32x4 __attribute__((ext_vector_type(4)));

__device__ __forceinline__ uint32_t f2bf(float f){
  union{float ff; uint32_t u;} v; v.ff=f;
  return (v.u + 0x7FFFu + ((v.u>>16)&1u))>>16;
}
__device__ __forceinline__ uint32_t pack2(float a, float b){
  return f2bf(a) | (f2bf(b)<<16);
}
__device__ __forceinline__ float sigm(float v){ return 1.f/(1.f+__expf(-v)); }

// -------- weight prep: Weff = W_g @ Wl_g[:64] (+bias row at K=129), stored as
// TRANSPOSED A-fragments: frag (g,kk,rt), lane=(kgrp,c16): row j = g*64+rt*16+c16,
// k = kk*32 + kgrp*8 + e (e=0..7). Wlf (frags 84..91): same for Wl_h[64:].
__global__ void k_prep(const float* Wz, const float* bz, const float* Wlz, const float* blz,
                       const float* Wr, const float* br, const float* Wlr, const float* blr,
                       const float* Wh, const float* bh, const float* Wlh, const float* blh,
                       uint16_t* WfT, uint16_t* Wlf)
{
  int idx = blockIdx.x*256 + threadIdx.x;
  if (idx < 192*224) {
    int j = idx / 224, k = idx - j*224;
    int g = j >> 6, jj = j & 63;
    const float* W  = g==0?Wz :(g==1?Wr :Wh);
    const float* Wl = g==0?Wlz:(g==1?Wlr:Wlh);
    const float* b  = g==0?bz :(g==1?br :bh);
    const float* bl = g==0?blz:(g==1?blr:blh);
    float v = 0.f;
    if (k < INC) {
      for (int m=0;m<64;m++) v += W[k*64+m]*Wl[m*64+jj];
    } else if (k == 129) {                       // bias row (AX ch129 == 1.0)
      v = bl[jj];
      for (int m=0;m<64;m++) v += b[m]*Wl[m*64+jj];
    } else if (k >= 160) {
      v = (g<2) ? Wl[(64+(k-160))*64 + jj] : 0.f;
    }
    int rt = jj>>4, c16 = jj&15;
    int kk = k>>5, kgrp = (k>>3)&3, e = k&7;
    int lane = kgrp*16 + c16;
    WfT[((((g*7+kk)*4+rt)*256 + lane*4 + (e>>1))<<1) + (e&1)] = (uint16_t)f2bf(v);
  } else if (idx < 192*224 + 4096) {
    int t2 = idx - 192*224; int j2 = t2>>6, k2 = t2&63;
    float v = Wlh[(64+k2)*64 + j2];
    int rt = j2>>4, c16 = j2&15;
    int kk2 = k2>>5, kgrp = (k2>>3)&3, e = k2&7;
    int lane = kgrp*16 + c16;
    Wlf[(((kk2*4+rt)*256 + lane*4 + (e>>1))<<1) + (e&1)] = (uint16_t)f2bf(v);
  }
}

__global__ void k_probs(const float* att, float* probs){
  if (threadIdx.x==0 && blockIdx.x==0){
    float m=-1e30f;
    for (int i=0;i<TP;i++) m = fmaxf(m, att[i]);
    float e[TP]; float s=0.f;
    for (int i=0;i<TP;i++){ e[i]=__expf(att[i]-m); s+=e[i]; }
    for (int i=0;i<TP;i++) probs[i]=e[i]/s;
  }
}

__global__ void k_hist(const int* eidx, int* deg){
  int e = blockIdx.x*256 + threadIdx.x;
  if (e < NE) atomicAdd(&deg[eidx[NE + e]], 1);   // dst row
}

__global__ void k_dinv(const int* deg, float* dinv){
  int n = blockIdx.x*256 + threadIdx.x;
  if (n < NND) dinv[n] = rsqrtf(1.0f + (float)deg[n]);
}

// ---- scan of padded row sizes p_i = (deg_i+1 rounded up to mult of 8) ----
__global__ void k_scan1(const int* deg, int* row_ptr, int* bsum){
  __shared__ int s[256];
  int tid = threadIdx.x;
  int i = blockIdx.x*256 + tid;
  int v = (i < NND) ? ((deg[i]+8)&~7) : 0;
  s[tid] = v; __syncthreads();
  for (int d=1; d<256; d<<=1){
    int t = (tid>=d) ? s[tid-d] : 0;
    __syncthreads();
    s[tid] += t; __syncthreads();
  }
  if (i < NND) row_ptr[i] = s[tid] - v;
  if (tid == 255) bsum[blockIdx.x] = s[255];
}
__global__ void k_scan2(int* bsum, int* boff, int* row_ptr){
  __shared__ int s[256];
  int tid = threadIdx.x;
  int v = (tid < NB_SCAN) ? bsum[tid] : 0;
  s[tid] = v; __syncthreads();
  for (int d=1; d<256; d<<=1){
    int t = (tid>=d) ? s[tid-d] : 0;
    __syncthreads();
    s[tid] += t; __syncthreads();
  }
  if (tid < NB_SCAN) boff[tid] = s[tid] - v;
  if (tid == NB_SCAN-1) row_ptr[NND] = s[tid];
}
__global__ void k_scan3(int* row_ptr, const int* boff){
  int i = blockIdx.x*256 + threadIdx.x;
  if (i < NND) row_ptr[i] += boff[blockIdx.x];
}

__global__ void k_fill(const int* eidx, const int* rp, int* cnt, uint16_t* csr){
  int e = blockIdx.x*256 + threadIdx.x;
  if (e < NE){
    int s = eidx[e], d = eidx[NE+e];
    int pos = rp[d] + atomicAdd(&cnt[d],1);
    csr[pos] = (uint16_t)s;
  }
}
// self-loop entry + sentinel padding (src=NND -> zero table row)
__global__ void k_self(const int* rp, const int* deg, uint16_t* csr){
  int n = blockIdx.x*256 + threadIdx.x;
  if (n < NND){
    int base = rp[n] + deg[n];
    int endp = rp[n+1];
    csr[base] = (uint16_t)n;
    for (int j=base+1; j<endp; j++) csr[j] = (uint16_t)NND;
  }
}

// x (N,129,25) fp32 -> tables pre-scaled by dinv[n]:
//   xT8[t][n][32 uints]  (ch 0..127 as fp8 e4m3, 128B rows = 1 cache line)
//   xsl[t][n] f32        (ch 128, exact)
__global__ __launch_bounds__(256) void k_transpose3(const float* __restrict__ x,
                                                    const float* __restrict__ dinv,
                                                    uint32_t* __restrict__ xT8,
                                                    float* __restrict__ xsl){
  __shared__ float lx[3232];           // 129*25 = 3225
  int n = blockIdx.x;
  const float* xr = x + (size_t)n*(INC*TP);
  for (int e=threadIdx.x; e<INC*TP; e+=256) lx[e] = xr[e];
  __syncthreads();
  float dv = dinv[n];
  for (int idx=threadIdx.x; idx<TP*32; idx+=256){
    int t = idx>>5, u = idx&31;
    int c0 = u*4;
    float v0 = lx[(c0+0)*TP+t]*dv, v1 = lx[(c0+1)*TP+t]*dv;
    float v2 = lx[(c0+2)*TP+t]*dv, v3 = lx[(c0+3)*TP+t]*dv;
    int wlo = __builtin_amdgcn_cvt_pk_fp8_f32(v0, v1, 0, false);
    int w   = __builtin_amdgcn_cvt_pk_fp8_f32(v2, v3, wlo, true);
    xT8[((size_t)t*NNDP + n)*32 + u] = (uint32_t)w;
  }
  for (int t=threadIdx.x; t<TP; t+=256)
    xsl[(size_t)t*NNDP + n] = dv*lx[128*TP + t];
  if (blockIdx.x == 0){                // zero the sentinel rows
    for (int idx=threadIdx.x; idx<TP*32; idx+=256){
      int t = idx>>5, u = idx&31;
      xT8[((size_t)t*NNDP + NND)*32 + u] = 0u;
    }
    for (int t=threadIdx.x; t<TP; t+=256) xsl[(size_t)t*NNDP + NND] = 0.f;
  }
}

// Aggregation, scheme D + fp8: wave per (dst,t); edges serial; per edge ONE
// wave-uniform coalesced 128B row load, scalar CSR via s_load, HW fp8 decode.
__global__ __launch_bounds__(256) void k_agg(const uint16_t* __restrict__ xT8,
    const int* __restrict__ rp, const uint16_t* __restrict__ csr,
    const float* __restrict__ dinv, uint32_t* __restrict__ AX)
{
  int t = blockIdx.y;
  int wave = threadIdx.x>>6, lane = threadIdx.x&63;
  int d = blockIdx.x*4 + wave;
  int beg = __builtin_amdgcn_readfirstlane(rp[d]);
  int end = __builtin_amdgcn_readfirstlane(rp[d+1]);
  const uint16_t* tbl = xT8 + (size_t)t*((size_t)NNDP*64);   // 64 ushorts/row
  float a0=0.f, a1=0.f;
  for (int i0=beg; i0<end; i0+=8){
    ulonglong2 c = *(const ulonglong2*)(csr + i0);   // uniform -> s_load
    #pragma unroll
    for (int k=0;k<4;k++){
      int s0 = (int)((c.x >> (k*16)) & 0xFFFFu);     // scalar extracts
      int s1 = (int)((c.y >> (k*16)) & 0xFFFFu);
      uint32_t u0 = tbl[(size_t)s0*64 + lane];       // 128B row, 1 line
      uint32_t u1 = tbl[(size_t)s1*64 + lane];
      f32x2 v0 = __builtin_amdgcn_cvt_pk_f32_fp8((int)u0, false);
      f32x2 v1 = __builtin_amdgcn_cvt_pk_f32_fp8((int)u1, false);
      a0 += v0.x; a1 += v0.y;
      a0 += v1.x; a1 += v1.y;
    }
  }
  float dv = dinv[d];
  AX[(size_t)t*((size_t)MPAD*80) + (size_t)d*80 + lane] = pack2(dv*a0, dv*a1);
}

// channel 128 (+ bias channel 129 = 1.0): thread per (dst,t)
__global__ void k_aggL(const float* __restrict__ xsl,
    const int* __restrict__ rp, const uint16_t* __restrict__ csr,
    const float* __restrict__ dinv, uint32_t* __restrict__ AX)
{
  int t = blockIdx.y;
  int d = blockIdx.x*256 + threadIdx.x;
  if (d >= NND) return;
  const float* pl = xsl + (size_t)t*NNDP;
  float a = 0.f;
  int beg=rp[d], end=rp[d+1];
  #pragma unroll 4
  for (int i=beg;i<end;i++) a += pl[(int)csr[i]];
  AX[(size_t)t*((size_t)MPAD*80) + (size_t)d*80 + 64] = pack2(dinv[d]*a, 1.0f);
}

// Cross-lane rebuild: C-layout (lane=node holds ch rt*16+q*4+j) -> B-frag
// (lane=node holds 8 consecutive ch at q*8 within a 32-ch block).
__device__ __forceinline__ u32x4 build_frag(uint32_t Pa0, uint32_t Pa1,
                                            uint32_t Pb0, uint32_t Pb1,
                                            int srcA, int srcB, bool rsel){
  uint32_t a0 = (uint32_t)__shfl((int)Pa0, srcA);
  uint32_t b0 = (uint32_t)__shfl((int)Pb0, srcA);
  uint32_t a1 = (uint32_t)__shfl((int)Pa1, srcA);
  uint32_t b1 = (uint32_t)__shfl((int)Pb1, srcA);
  uint32_t a2 = (uint32_t)__shfl((int)Pa0, srcB);
  uint32_t b2 = (uint32_t)__shfl((int)Pb0, srcB);
  uint32_t a3 = (uint32_t)__shfl((int)Pa1, srcB);
  uint32_t b3 = (uint32_t)__shfl((int)Pb1, srcB);
  u32x4 o;
  o.x = rsel?b0:a0; o.y = rsel?b1:a1; o.z = rsel?b2:a2; o.w = rsel?b3:a3;
  return o;
}

// Fused full recurrence, TRANSPOSED + LDS-staged weights: 8 waves/block,
// each wave owns 16 nodes for all 25 steps. Weights (92 KB) staged to LDS
// once per block; H/HR in registers; AX via nontemporal loads; one barrier.
__global__ __launch_bounds__(512, 2) void k_gru(const uint32_t* __restrict__ AX,
    const uint32_t* __restrict__ Wall, float* __restrict__ accum,
    const float* __restrict__ probs)
{
  extern __shared__ uint32_t ldsW[];          // NFRAG x 256 dwords
  int tid = threadIdx.x;
  int lane = tid & 63, wave = tid >> 6;
  int c16 = lane & 15, q = lane >> 4;
  int node = blockIdx.x*128 + wave*16 + c16;
  bool rsel = (q & 2) != 0;
  int srcA = ((2*q)&3)*16 + c16;
  int srcB = ((2*q+1)&3)*16 + c16;

  // stage all weight fragments (coalesced b128)
  {
    const u32x4* src = (const u32x4*)Wall;
    u32x4* dst = (u32x4*)ldsW;
    for (int i = tid; i < NFRAG*64; i += 512) dst[i] = src[i];
  }
  __syncthreads();

  f32x4 h[4] = {};                      // H[node][rt*16+q*4+j], f32 state
  f32x4 acr[4] = {};                    // attention accumulator
  u32x4 hf0 = {0,0,0,0}, hf1 = {0,0,0,0};  // H as bf16 B-frags (k 160..223)

  for (int t=0; t<TP; t++){
    const uint32_t* AXrow = AX + (size_t)t*((size_t)MPAD*80) + (size_t)node*80 + q*4;
    bf16x8 ax0 = __builtin_nontemporal_load((const bf16x8*)(AXrow));
    bf16x8 ax1 = __builtin_nontemporal_load((const bf16x8*)(AXrow+16));
    bf16x8 ax2 = __builtin_nontemporal_load((const bf16x8*)(AXrow+32));
    bf16x8 ax3 = __builtin_nontemporal_load((const bf16x8*)(AXrow+48));
    bf16x8 ax4 = __builtin_nontemporal_load((const bf16x8*)(AXrow+64));

    f32x4 accg[3][4] = {};
    #pragma unroll
    for (int kk=0; kk<7; kk++){
      bf16x8 xv;
      if      (kk==0) xv = ax0;
      else if (kk==1) xv = ax1;
      else if (kk==2) xv = ax2;
      else if (kk==3) xv = ax3;
      else if (kk==4) xv = ax4;
      else if (kk==5) xv = __builtin_bit_cast(bf16x8, hf0);
      else            xv = __builtin_bit_cast(bf16x8, hf1);
      #pragma unroll
      for (int g=0; g<3; g++){
        if (g==2 && kk>=5) continue;       // zero weight block
        #pragma unroll
        for (int rt=0; rt<4; rt++){
          bf16x8 wv = *(const bf16x8*)&ldsW[(((g*7+kk)*4+rt)<<8) + lane*4];
          accg[g][rt] = __builtin_amdgcn_mfma_f32_16x16x32_bf16(wv, xv, accg[g][rt],0,0,0);
        }
      }
    }

    // epilogue A: z (into accg[0]), r -> HR packed pairs (lane-local)
    uint32_t Phr[4][2];
    #pragma unroll
    for (int rt=0; rt<4; rt++){
      float hrv[4];
      #pragma unroll
      for (int j=0;j<4;j++){
        float z = sigm(accg[0][rt][j]);
        float r = sigm(accg[1][rt][j]);
        accg[0][rt][j] = z;
        hrv[j] = h[rt][j]*r;
      }
      Phr[rt][0] = pack2(hrv[0], hrv[1]);
      Phr[rt][1] = pack2(hrv[2], hrv[3]);
    }
    u32x4 hrf0 = build_frag(Phr[0][0],Phr[0][1],Phr[1][0],Phr[1][1], srcA,srcB,rsel);
    u32x4 hrf1 = build_frag(Phr[2][0],Phr[2][1],Phr[3][0],Phr[3][1], srcA,srcB,rsel);

    // GEMM2^T: Wl_h^T @ HR^T
    f32x4 acc2[4] = {};
    #pragma unroll
    for (int kk2=0; kk2<2; kk2++){
      bf16x8 bv = __builtin_bit_cast(bf16x8, kk2 ? hrf1 : hrf0);
      #pragma unroll
      for (int rt=0; rt<4; rt++){
        bf16x8 wv = *(const bf16x8*)&ldsW[((84+kk2*4+rt)<<8) + lane*4];
        acc2[rt] = __builtin_amdgcn_mfma_f32_16x16x32_bf16(wv, bv, acc2[rt],0,0,0);
      }
    }

    // epilogue B: GRU update, attention accum, rebuild H frags
    float pt = probs[t];
    uint32_t Ph[4][2];
    #pragma unroll
    for (int rt=0; rt<4; rt++){
      #pragma unroll
      for (int j=0;j<4;j++){
        float ht = tanhf(acc2[rt][j] + accg[2][rt][j]);
        float z  = accg[0][rt][j];
        float hn = z*h[rt][j] + (1.f-z)*ht;
        h[rt][j] = hn;
        acr[rt][j] += pt*hn;
      }
      Ph[rt][0] = pack2(h[rt][0], h[rt][1]);
      Ph[rt][1] = pack2(h[rt][2], h[rt][3]);
    }
    hf0 = build_frag(Ph[0][0],Ph[0][1],Ph[1][0],Ph[1][1], srcA,srcB,rsel);
    hf1 = build_frag(Ph[2][0],Ph[2][1],Ph[3][0],Ph[3][1], srcA,srcB,rsel);
  }

  if (node < NND){
    #pragma unroll
    for (int rt=0; rt<4; rt++)
      *(f32x4*)&accum[(size_t)node*64 + rt*16 + q*4] = acr[rt];
  }
}

__global__ void k_out(const int* train_idx, const float* accum, const float* Wo,
                      const float* bo, const float* y, float* out){
  int i = blockIdx.x*256 + threadIdx.x;
  if (i < NTR){
    int n = train_idx[i];
    float s = bo[0];
    const float* ar = accum + (size_t)n*64;
    #pragma unroll
    for (int j=0;j<64;j++) s += ar[j]*Wo[j];
    out[i] = sigm(s);
    out[NTR+i] = y[n];
  }
}

extern "C" void kernel_launch(void* const* d_in, const int* in_sizes, int n_in,
                              void* d_out, int out_size, void* d_ws, size_t ws_size,
                              hipStream_t stream)
{
  const float* x   = (const float*)d_in[0];
  const int*   eix = (const int*)d_in[1];
  const float* y   = (const float*)d_in[2];
  const int*   tri = (const int*)d_in[3];
  const float* Wz  = (const float*)d_in[4];
  const float* bz  = (const float*)d_in[5];
  const float* Wlz = (const float*)d_in[6];
  const float* blz = (const float*)d_in[7];
  const float* Wr  = (const float*)d_in[8];
  const float* br  = (const float*)d_in[9];
  const float* Wlr = (const float*)d_in[10];
  const float* blr = (const float*)d_in[11];
  const float* Wh  = (const float*)d_in[12];
  const float* bh  = (const float*)d_in[13];
  const float* Wlh = (const float*)d_in[14];
  const float* blh = (const float*)d_in[15];
  const float* att = (const float*)d_in[16];
  const float* Wo  = (const float*)d_in[17];
  const float* bo  = (const float*)d_in[18];
  float* out = (float*)d_out;

  char* w = (char*)d_ws;
  size_t off = 0;
  auto alloc = [&](size_t sz)->size_t{ size_t o=off; off=(off+sz+255)&~(size_t)255; return o; };

  // --- zero block (one small memset) ---
  size_t zo = off;
  size_t o_deg   = alloc((size_t)NND*4);
  size_t o_cnt   = alloc((size_t)NND*4);
  size_t zlen = off - zo;
  // --- rest ---
  size_t o_dinv  = alloc((size_t)NND*4);
  size_t o_rp    = alloc((size_t)(NND+1)*4);
  size_t o_bsum  = alloc((size_t)NB_SCAN*4);
  size_t o_boff  = alloc((size_t)NB_SCAN*4);
  size_t o_csr   = alloc((size_t)CSR_MAX*2);
  size_t o_Wall  = alloc((size_t)NFRAG*1024);     // 84 gate frags + 8 Wl frags
  size_t o_probs = alloc((size_t)TP*4);
  size_t o_accum = alloc((size_t)MPAD*64*4);
  size_t o_AX    = alloc((size_t)TP*MPAD*80*4);   // 400 MB, all t
  size_t o_xT8   = alloc((size_t)TP*NNDP*128);    // 160 MB (fp8 table)
  size_t o_xl    = alloc((size_t)TP*NNDP*4);      // 5 MB
  (void)ws_size; (void)in_sizes; (void)n_in; (void)out_size;

  int*      deg   = (int*)(w+o_deg);
  int*      cnt   = (int*)(w+o_cnt);
  float*    dinv  = (float*)(w+o_dinv);
  int*      rp    = (int*)(w+o_rp);
  int*      bsum  = (int*)(w+o_bsum);
  int*      boff  = (int*)(w+o_boff);
  uint16_t* csr   = (uint16_t*)(w+o_csr);
  uint16_t* WfT   = (uint16_t*)(w+o_Wall);
  uint16_t* Wlf   = WfT + 84*512;                 // frags 84..91
  float*    probs = (float*)(w+o_probs);
  float*    accum = (float*)(w+o_accum);
  uint32_t* AX    = (uint32_t*)(w+o_AX);
  uint32_t* xT8   = (uint32_t*)(w+o_xT8);
  float*    xsl   = (float*)(w+o_xl);

  hipMemsetAsync(w+zo, 0, zlen, stream);

  k_prep<<<(192*224 + 4096 + 255)/256, 256, 0, stream>>>(
      Wz,bz,Wlz,blz, Wr,br,Wlr,blr, Wh,bh,Wlh,blh, WfT, Wlf);
  k_probs<<<1, 64, 0, stream>>>(att, probs);
  k_hist<<<(NE+255)/256, 256, 0, stream>>>(eix, deg);
  k_dinv<<<(NND+255)/256, 256, 0, stream>>>(deg, dinv);
  k_scan1<<<NB_SCAN, 256, 0, stream>>>(deg, rp, bsum);
  k_scan2<<<1, 256, 0, stream>>>(bsum, boff, rp);
  k_scan3<<<NB_SCAN, 256, 0, stream>>>(rp, boff);
  k_fill<<<(NE+255)/256, 256, 0, stream>>>(eix, rp, cnt, csr);
  k_self<<<NB_SCAN, 256, 0, stream>>>(rp, deg, csr);
  k_transpose3<<<NND, 256, 0, stream>>>(x, dinv, xT8, xsl);

  k_agg <<<dim3(12500, TP), 256, 0, stream>>>((const uint16_t*)xT8, rp, csr, dinv, AX);
  k_aggL<<<dim3(NB_SCAN, TP), 256, 0, stream>>>(xsl, rp, csr, dinv, AX);

  static bool attr_set = false;
  if (!attr_set){
    hipFuncSetAttribute((const void*)k_gru,
        hipFuncAttributeMaxDynamicSharedMemorySize, WLDS_BYTES);
    attr_set = true;
  }
  k_gru<<<MPAD/128, 512, WLDS_BYTES, stream>>>(AX, (const uint32_t*)WfT, accum, probs);
  k_out<<<(NTR+255)/256, 256, 0, stream>>>(tri, accum, Wo, bo, y, out);
}

// Round 11
// 2052.140 us; speedup vs baseline: 1.2845x; 1.1004x over previous
//
#include <hip/hip_runtime.h>
#include <stdint.h>

#define NND 50000
#define NNDP 50016            // table row-stride (sentinel zero row at index NND)
#define NE  1600000
#define INC 129
#define TP  25
#define NTR 25000
#define MPAD 50048
#define NB_SCAN 196           // ceil(50000/256)
#define CSR_MAX (NE + 8*NND + 128)
#define NFRAG 92              // 84 gate fragments + 8 Wl_h fragments
#define WLDS_BYTES (NFRAG*1024)

typedef short bf16x8 __attribute__((ext_vector_type(8)));
typedef float f32x4 __attribute__((ext_vector_type(4)));
typedef float f32x2 __attribute__((ext_vector_type(2)));
typedef uint32_t u32x4 __attribute__((ext_vector_type(4)));

__device__ __forceinline__ uint32_t f2bf(float f){
  union{float ff; uint32_t u;} v; v.ff=f;
  return (v.u + 0x7FFFu + ((v.u>>16)&1u))>>16;
}
__device__ __forceinline__ uint32_t pack2(float a, float b){
  return f2bf(a) | (f2bf(b)<<16);
}
__device__ __forceinline__ float sigm(float v){ return 1.f/(1.f+__expf(-v)); }

// -------- weight prep: Weff = W_g @ Wl_g[:64] (+bias row at K=129), stored as
// TRANSPOSED A-fragments: frag (g,kk,rt), lane=(kgrp,c16): row j = g*64+rt*16+c16,
// k = kk*32 + kgrp*8 + e (e=0..7). Wlf (frags 84..91): same for Wl_h[64:].
__global__ void k_prep(const float* Wz, const float* bz, const float* Wlz, const float* blz,
                       const float* Wr, const float* br, const float* Wlr, const float* blr,
                       const float* Wh, const float* bh, const float* Wlh, const float* blh,
                       uint16_t* WfT, uint16_t* Wlf)
{
  int idx = blockIdx.x*256 + threadIdx.x;
  if (idx < 192*224) {
    int j = idx / 224, k = idx - j*224;
    int g = j >> 6, jj = j & 63;
    const float* W  = g==0?Wz :(g==1?Wr :Wh);
    const float* Wl = g==0?Wlz:(g==1?Wlr:Wlh);
    const float* b  = g==0?bz :(g==1?br :bh);
    const float* bl = g==0?blz:(g==1?blr:blh);
    float v = 0.f;
    if (k < INC) {
      for (int m=0;m<64;m++) v += W[k*64+m]*Wl[m*64+jj];
    } else if (k == 129) {                       // bias row (kk=4 frag ch129 == 1.0)
      v = bl[jj];
      for (int m=0;m<64;m++) v += b[m]*Wl[m*64+jj];
    } else if (k >= 160) {
      v = (g<2) ? Wl[(64+(k-160))*64 + jj] : 0.f;
    }
    int rt = jj>>4, c16 = jj&15;
    int kk = k>>5, kgrp = (k>>3)&3, e = k&7;
    int lane = kgrp*16 + c16;
    WfT[((((g*7+kk)*4+rt)*256 + lane*4 + (e>>1))<<1) + (e&1)] = (uint16_t)f2bf(v);
  } else if (idx < 192*224 + 4096) {
    int t2 = idx - 192*224; int j2 = t2>>6, k2 = t2&63;
    float v = Wlh[(64+k2)*64 + j2];
    int rt = j2>>4, c16 = j2&15;
    int kk2 = k2>>5, kgrp = (k2>>3)&3, e = k2&7;
    int lane = kgrp*16 + c16;
    Wlf[(((kk2*4+rt)*256 + lane*4 + (e>>1))<<1) + (e&1)] = (uint16_t)f2bf(v);
  }
}

__global__ void k_probs(const float* att, float* probs){
  if (threadIdx.x==0 && blockIdx.x==0){
    float m=-1e30f;
    for (int i=0;i<TP;i++) m = fmaxf(m, att[i]);
    float e[TP]; float s=0.f;
    for (int i=0;i<TP;i++){ e[i]=__expf(att[i]-m); s+=e[i]; }
    for (int i=0;i<TP;i++) probs[i]=e[i]/s;
  }
}

__global__ void k_hist(const int* eidx, int* deg){
  int e = blockIdx.x*256 + threadIdx.x;
  if (e < NE) atomicAdd(&deg[eidx[NE + e]], 1);   // dst row
}

__global__ void k_dinv(const int* deg, float* dinv){
  int n = blockIdx.x*256 + threadIdx.x;
  if (n < NND) dinv[n] = rsqrtf(1.0f + (float)deg[n]);
}

// ---- scan of padded row sizes p_i = (deg_i+1 rounded up to mult of 8) ----
__global__ void k_scan1(const int* deg, int* row_ptr, int* bsum){
  __shared__ int s[256];
  int tid = threadIdx.x;
  int i = blockIdx.x*256 + tid;
  int v = (i < NND) ? ((deg[i]+8)&~7) : 0;
  s[tid] = v; __syncthreads();
  for (int d=1; d<256; d<<=1){
    int t = (tid>=d) ? s[tid-d] : 0;
    __syncthreads();
    s[tid] += t; __syncthreads();
  }
  if (i < NND) row_ptr[i] = s[tid] - v;
  if (tid == 255) bsum[blockIdx.x] = s[255];
}
__global__ void k_scan2(int* bsum, int* boff, int* row_ptr){
  __shared__ int s[256];
  int tid = threadIdx.x;
  int v = (tid < NB_SCAN) ? bsum[tid] : 0;
  s[tid] = v; __syncthreads();
  for (int d=1; d<256; d<<=1){
    int t = (tid>=d) ? s[tid-d] : 0;
    __syncthreads();
    s[tid] += t; __syncthreads();
  }
  if (tid < NB_SCAN) boff[tid] = s[tid] - v;
  if (tid == NB_SCAN-1) row_ptr[NND] = s[tid];
}
__global__ void k_scan3(int* row_ptr, const int* boff){
  int i = blockIdx.x*256 + threadIdx.x;
  if (i < NND) row_ptr[i] += boff[blockIdx.x];
}

__global__ void k_fill(const int* eidx, const int* rp, int* cnt, uint16_t* csr){
  int e = blockIdx.x*256 + threadIdx.x;
  if (e < NE){
    int s = eidx[e], d = eidx[NE+e];
    int pos = rp[d] + atomicAdd(&cnt[d],1);
    csr[pos] = (uint16_t)s;
  }
}
// self-loop entry + sentinel padding (src=NND -> zero table row)
__global__ void k_self(const int* rp, const int* deg, uint16_t* csr){
  int n = blockIdx.x*256 + threadIdx.x;
  if (n < NND){
    int base = rp[n] + deg[n];
    int endp = rp[n+1];
    csr[base] = (uint16_t)n;
    for (int j=base+1; j<endp; j++) csr[j] = (uint16_t)NND;
  }
}

// x (N,129,25) fp32 -> tables pre-scaled by dinv[n]:
//   xT8[t][n][32 uints]  (ch 0..127 as fp8 e4m3, 128B rows = 1 cache line)
//   xsl[t][n] f32        (ch 128, exact)
__global__ __launch_bounds__(256) void k_transpose3(const float* __restrict__ x,
                                                    const float* __restrict__ dinv,
                                                    uint32_t* __restrict__ xT8,
                                                    float* __restrict__ xsl){
  __shared__ float lx[3232];           // 129*25 = 3225
  int n = blockIdx.x;
  const float* xr = x + (size_t)n*(INC*TP);
  for (int e=threadIdx.x; e<INC*TP; e+=256) lx[e] = xr[e];
  __syncthreads();
  float dv = dinv[n];
  for (int idx=threadIdx.x; idx<TP*32; idx+=256){
    int t = idx>>5, u = idx&31;
    int c0 = u*4;
    float v0 = lx[(c0+0)*TP+t]*dv, v1 = lx[(c0+1)*TP+t]*dv;
    float v2 = lx[(c0+2)*TP+t]*dv, v3 = lx[(c0+3)*TP+t]*dv;
    int wlo = __builtin_amdgcn_cvt_pk_fp8_f32(v0, v1, 0, false);
    int w   = __builtin_amdgcn_cvt_pk_fp8_f32(v2, v3, wlo, true);
    xT8[((size_t)t*NNDP + n)*32 + u] = (uint32_t)w;
  }
  for (int t=threadIdx.x; t<TP; t+=256)
    xsl[(size_t)t*NNDP + n] = dv*lx[128*TP + t];
  if (blockIdx.x == 0){                // zero the sentinel rows
    for (int idx=threadIdx.x; idx<TP*32; idx+=256){
      int t = idx>>5, u = idx&31;
      xT8[((size_t)t*NNDP + NND)*32 + u] = 0u;
    }
    for (int t=threadIdx.x; t<TP; t+=256) xsl[(size_t)t*NNDP + NND] = 0.f;
  }
}

// Aggregation, scheme D + fp8: wave per (dst,t); edges serial; per edge ONE
// wave-uniform coalesced 128B row load, scalar CSR via s_load, HW fp8 decode.
// Output AX0: 256B line-aligned rows (ch 0..127 bf16 pairs).
__global__ __launch_bounds__(256) void k_agg(const uint16_t* __restrict__ xT8,
    const int* __restrict__ rp, const uint16_t* __restrict__ csr,
    const float* __restrict__ dinv, uint32_t* __restrict__ AX0)
{
  int t = blockIdx.y;
  int wave = threadIdx.x>>6, lane = threadIdx.x&63;
  int d = blockIdx.x*4 + wave;
  int beg = __builtin_amdgcn_readfirstlane(rp[d]);
  int end = __builtin_amdgcn_readfirstlane(rp[d+1]);
  const uint16_t* tbl = xT8 + (size_t)t*((size_t)NNDP*64);   // 64 ushorts/row
  float a0=0.f, a1=0.f;
  for (int i0=beg; i0<end; i0+=8){
    ulonglong2 c = *(const ulonglong2*)(csr + i0);   // uniform -> s_load
    #pragma unroll
    for (int k=0;k<4;k++){
      int s0 = (int)((c.x >> (k*16)) & 0xFFFFu);     // scalar extracts
      int s1 = (int)((c.y >> (k*16)) & 0xFFFFu);
      uint32_t u0 = tbl[(size_t)s0*64 + lane];       // 128B row, 1 line
      uint32_t u1 = tbl[(size_t)s1*64 + lane];
      f32x2 v0 = __builtin_amdgcn_cvt_pk_f32_fp8((int)u0, false);
      f32x2 v1 = __builtin_amdgcn_cvt_pk_f32_fp8((int)u1, false);
      a0 += v0.x; a1 += v0.y;
      a0 += v1.x; a1 += v1.y;
    }
  }
  float dv = dinv[d];
  AX0[((size_t)t*MPAD + d)*64 + lane] = pack2(dv*a0, dv*a1);
}

// channel 128: thread per (dst,t); output scalar f32 plane AXL[t][d]
__global__ void k_aggL(const float* __restrict__ xsl,
    const int* __restrict__ rp, const uint16_t* __restrict__ csr,
    const float* __restrict__ dinv, float* __restrict__ AXL)
{
  int t = blockIdx.y;
  int d = blockIdx.x*256 + threadIdx.x;
  if (d >= NND) return;
  const float* pl = xsl + (size_t)t*NNDP;
  float a = 0.f;
  int beg=rp[d], end=rp[d+1];
  #pragma unroll 4
  for (int i=beg;i<end;i++) a += pl[(int)csr[i]];
  AXL[(size_t)t*MPAD + d] = dinv[d]*a;
}

// Cross-lane rebuild: C-layout (lane=node holds ch rt*16+q*4+j) -> B-frag
// (lane=node holds 8 consecutive ch at q*8 within a 32-ch block).
__device__ __forceinline__ u32x4 build_frag(uint32_t Pa0, uint32_t Pa1,
                                            uint32_t Pb0, uint32_t Pb1,
                                            int srcA, int srcB, bool rsel){
  uint32_t a0 = (uint32_t)__shfl((int)Pa0, srcA);
  uint32_t b0 = (uint32_t)__shfl((int)Pb0, srcA);
  uint32_t a1 = (uint32_t)__shfl((int)Pa1, srcA);
  uint32_t b1 = (uint32_t)__shfl((int)Pb1, srcA);
  uint32_t a2 = (uint32_t)__shfl((int)Pa0, srcB);
  uint32_t b2 = (uint32_t)__shfl((int)Pb0, srcB);
  uint32_t a3 = (uint32_t)__shfl((int)Pa1, srcB);
  uint32_t b3 = (uint32_t)__shfl((int)Pb1, srcB);
  u32x4 o;
  o.x = rsel?b0:a0; o.y = rsel?b1:a1; o.z = rsel?b2:a2; o.w = rsel?b3:a3;
  return o;
}

// One gate's transposed GEMM: acc[rt] += W(g)^T-frag x activation-frag.
template<int G, int KMAX>
__device__ __forceinline__ void gate_gemm(const uint32_t* ldsW, int lane,
    bf16x8 ax0, bf16x8 ax1, bf16x8 ax2, bf16x8 ax3, bf16x8 ax4,
    u32x4 hf0, u32x4 hf1, f32x4* acc)
{
  #pragma unroll
  for (int kk=0; kk<KMAX; kk++){
    bf16x8 xv = (kk==0)?ax0:(kk==1)?ax1:(kk==2)?ax2:(kk==3)?ax3:(kk==4)?ax4:
                (kk==5)?__builtin_bit_cast(bf16x8,hf0):__builtin_bit_cast(bf16x8,hf1);
    #pragma unroll
    for (int rt=0; rt<4; rt++){
      bf16x8 wv = *(const bf16x8*)&ldsW[(((G*7+kk)*4+rt)<<8) + lane*4];
      acc[rt] = __builtin_amdgcn_mfma_f32_16x16x32_bf16(wv, xv, acc[rt],0,0,0);
    }
  }
}

// Fused full recurrence, TRANSPOSED + LDS-staged weights: 8 waves/block,
// each wave owns 16 nodes for all 25 steps. Sequential-gate GEMMs keep
// peak VGPR ~110 (no spills); AX0 reads cached & line-aligned; kk=4 frag
// ([ch128,bias,0..]) constructed in registers. One barrier total.
__global__ __launch_bounds__(512, 2) void k_gru(const uint32_t* __restrict__ AX0,
    const float* __restrict__ AXL, const uint32_t* __restrict__ Wall,
    float* __restrict__ accum, const float* __restrict__ probs)
{
  extern __shared__ uint32_t ldsW[];          // NFRAG x 256 dwords
  int tid = threadIdx.x;
  int lane = tid & 63, wave = tid >> 6;
  int c16 = lane & 15, q = lane >> 4;
  int node = blockIdx.x*128 + wave*16 + c16;
  bool rsel = (q & 2) != 0;
  int srcA = ((2*q)&3)*16 + c16;
  int srcB = ((2*q+1)&3)*16 + c16;

  // stage all weight fragments (coalesced b128)
  {
    const u32x4* src = (const u32x4*)Wall;
    u32x4* dst = (u32x4*)ldsW;
    for (int i = tid; i < NFRAG*64; i += 512) dst[i] = src[i];
  }
  __syncthreads();

  f32x4 h[4] = {};                      // H[node][rt*16+q*4+j], f32 state
  f32x4 acr[4] = {};                    // attention accumulator
  u32x4 hf0 = {0,0,0,0}, hf1 = {0,0,0,0};  // H as bf16 B-frags (k 160..223)

  for (int t=0; t<TP; t++){
    const uint32_t* AXrow = AX0 + ((size_t)t*MPAD + node)*64 + q*4;
    bf16x8 ax0 = *(const bf16x8*)(AXrow);
    bf16x8 ax1 = *(const bf16x8*)(AXrow+16);
    bf16x8 ax2 = *(const bf16x8*)(AXrow+32);
    bf16x8 ax3 = *(const bf16x8*)(AXrow+48);
    float axl = AXL[(size_t)t*MPAD + node];
    u32x4 x4u = {0,0,0,0};
    if (q == 0) x4u.x = pack2(axl, 1.0f);
    bf16x8 ax4 = __builtin_bit_cast(bf16x8, x4u);

    // gate z
    f32x4 za[4] = {};
    gate_gemm<0,7>(ldsW, lane, ax0,ax1,ax2,ax3,ax4, hf0, hf1, za);
    #pragma unroll
    for (int rt=0; rt<4; rt++)
      #pragma unroll
      for (int j=0;j<4;j++) za[rt][j] = sigm(za[rt][j]);

    // gate r -> HR fragments (r consumed immediately)
    f32x4 ra[4] = {};
    gate_gemm<1,7>(ldsW, lane, ax0,ax1,ax2,ax3,ax4, hf0, hf1, ra);
    uint32_t Phr[4][2];
    #pragma unroll
    for (int rt=0; rt<4; rt++){
      float hr0 = h[rt][0]*sigm(ra[rt][0]);
      float hr1 = h[rt][1]*sigm(ra[rt][1]);
      float hr2 = h[rt][2]*sigm(ra[rt][2]);
      float hr3 = h[rt][3]*sigm(ra[rt][3]);
      Phr[rt][0] = pack2(hr0, hr1);
      Phr[rt][1] = pack2(hr2, hr3);
    }
    u32x4 hrf0 = build_frag(Phr[0][0],Phr[0][1],Phr[1][0],Phr[1][1], srcA,srcB,rsel);
    u32x4 hrf1 = build_frag(Phr[2][0],Phr[2][1],Phr[3][0],Phr[3][1], srcA,srcB,rsel);

    // gate h preact (X part only; H-part weights are zero)
    f32x4 ph[4] = {};
    gate_gemm<2,5>(ldsW, lane, ax0,ax1,ax2,ax3,ax4, hf0, hf1, ph);

    // GEMM2^T: Wl_h^T @ HR^T
    f32x4 acc2[4] = {};
    #pragma unroll
    for (int kk2=0; kk2<2; kk2++){
      bf16x8 bv = __builtin_bit_cast(bf16x8, kk2 ? hrf1 : hrf0);
      #pragma unroll
      for (int rt=0; rt<4; rt++){
        bf16x8 wv = *(const bf16x8*)&ldsW[((84+kk2*4+rt)<<8) + lane*4];
        acc2[rt] = __builtin_amdgcn_mfma_f32_16x16x32_bf16(wv, bv, acc2[rt],0,0,0);
      }
    }

    // epilogue: GRU update, attention accum, rebuild H frags
    float pt = probs[t];
    uint32_t Ph[4][2];
    #pragma unroll
    for (int rt=0; rt<4; rt++){
      #pragma unroll
      for (int j=0;j<4;j++){
        float ht = tanhf(acc2[rt][j] + ph[rt][j]);
        float z  = za[rt][j];
        float hn = z*h[rt][j] + (1.f-z)*ht;
        h[rt][j] = hn;
        acr[rt][j] += pt*hn;
      }
      Ph[rt][0] = pack2(h[rt][0], h[rt][1]);
      Ph[rt][1] = pack2(h[rt][2], h[rt][3]);
    }
    hf0 = build_frag(Ph[0][0],Ph[0][1],Ph[1][0],Ph[1][1], srcA,srcB,rsel);
    hf1 = build_frag(Ph[2][0],Ph[2][1],Ph[3][0],Ph[3][1], srcA,srcB,rsel);
  }

  if (node < NND){
    #pragma unroll
    for (int rt=0; rt<4; rt++)
      *(f32x4*)&accum[(size_t)node*64 + rt*16 + q*4] = acr[rt];
  }
}

__global__ void k_out(const int* train_idx, const float* accum, const float* Wo,
                      const float* bo, const float* y, float* out){
  int i = blockIdx.x*256 + threadIdx.x;
  if (i < NTR){
    int n = train_idx[i];
    float s = bo[0];
    const float* ar = accum + (size_t)n*64;
    #pragma unroll
    for (int j=0;j<64;j++) s += ar[j]*Wo[j];
    out[i] = sigm(s);
    out[NTR+i] = y[n];
  }
}

extern "C" void kernel_launch(void* const* d_in, const int* in_sizes, int n_in,
                              void* d_out, int out_size, void* d_ws, size_t ws_size,
                              hipStream_t stream)
{
  const float* x   = (const float*)d_in[0];
  const int*   eix = (const int*)d_in[1];
  const float* y   = (const float*)d_in[2];
  const int*   tri = (const int*)d_in[3];
  const float* Wz  = (const float*)d_in[4];
  const float* bz  = (const float*)d_in[5];
  const float* Wlz = (const float*)d_in[6];
  const float* blz = (const float*)d_in[7];
  const float* Wr  = (const float*)d_in[8];
  const float* br  = (const float*)d_in[9];
  const float* Wlr = (const float*)d_in[10];
  const float* blr = (const float*)d_in[11];
  const float* Wh  = (const float*)d_in[12];
  const float* bh  = (const float*)d_in[13];
  const float* Wlh = (const float*)d_in[14];
  const float* blh = (const float*)d_in[15];
  const float* att = (const float*)d_in[16];
  const float* Wo  = (const float*)d_in[17];
  const float* bo  = (const float*)d_in[18];
  float* out = (float*)d_out;

  char* w = (char*)d_ws;
  size_t off = 0;
  auto alloc = [&](size_t sz)->size_t{ size_t o=off; off=(off+sz+255)&~(size_t)255; return o; };

  // --- zero block (one small memset) ---
  size_t zo = off;
  size_t o_deg   = alloc((size_t)NND*4);
  size_t o_cnt   = alloc((size_t)NND*4);
  size_t zlen = off - zo;
  // --- rest ---
  size_t o_dinv  = alloc((size_t)NND*4);
  size_t o_rp    = alloc((size_t)(NND+1)*4);
  size_t o_bsum  = alloc((size_t)NB_SCAN*4);
  size_t o_boff  = alloc((size_t)NB_SCAN*4);
  size_t o_csr   = alloc((size_t)CSR_MAX*2);
  size_t o_Wall  = alloc((size_t)NFRAG*1024);     // 84 gate frags + 8 Wl frags
  size_t o_probs = alloc((size_t)TP*4);
  size_t o_accum = alloc((size_t)MPAD*64*4);
  size_t o_AX0   = alloc((size_t)TP*MPAD*256);    // 320 MB, ch 0..127, all t
  size_t o_AXL   = alloc((size_t)TP*MPAD*4);      // 5 MB, ch 128 (f32)
  size_t o_xT8   = alloc((size_t)TP*NNDP*128);    // 160 MB (fp8 table)
  size_t o_xl    = alloc((size_t)TP*NNDP*4);      // 5 MB
  (void)ws_size; (void)in_sizes; (void)n_in; (void)out_size;

  int*      deg   = (int*)(w+o_deg);
  int*      cnt   = (int*)(w+o_cnt);
  float*    dinv  = (float*)(w+o_dinv);
  int*      rp    = (int*)(w+o_rp);
  int*      bsum  = (int*)(w+o_bsum);
  int*      boff  = (int*)(w+o_boff);
  uint16_t* csr   = (uint16_t*)(w+o_csr);
  uint16_t* WfT   = (uint16_t*)(w+o_Wall);
  uint16_t* Wlf   = WfT + 84*512;                 // frags 84..91
  float*    probs = (float*)(w+o_probs);
  float*    accum = (float*)(w+o_accum);
  uint32_t* AX0   = (uint32_t*)(w+o_AX0);
  float*    AXL   = (float*)(w+o_AXL);
  uint32_t* xT8   = (uint32_t*)(w+o_xT8);
  float*    xsl   = (float*)(w+o_xl);

  hipMemsetAsync(w+zo, 0, zlen, stream);

  k_prep<<<(192*224 + 4096 + 255)/256, 256, 0, stream>>>(
      Wz,bz,Wlz,blz, Wr,br,Wlr,blr, Wh,bh,Wlh,blh, WfT, Wlf);
  k_probs<<<1, 64, 0, stream>>>(att, probs);
  k_hist<<<(NE+255)/256, 256, 0, stream>>>(eix, deg);
  k_dinv<<<(NND+255)/256, 256, 0, stream>>>(deg, dinv);
  k_scan1<<<NB_SCAN, 256, 0, stream>>>(deg, rp, bsum);
  k_scan2<<<1, 256, 0, stream>>>(bsum, boff, rp);
  k_scan3<<<NB_SCAN, 256, 0, stream>>>(rp, boff);
  k_fill<<<(NE+255)/256, 256, 0, stream>>>(eix, rp, cnt, csr);
  k_self<<<NB_SCAN, 256, 0, stream>>>(rp, deg, csr);
  k_transpose3<<<NND, 256, 0, stream>>>(x, dinv, xT8, xsl);

  k_agg <<<dim3(12500, TP), 256, 0, stream>>>((const uint16_t*)xT8, rp, csr, dinv, AX0);
  k_aggL<<<dim3(NB_SCAN, TP), 256, 0, stream>>>(xsl, rp, csr, dinv, AXL);

  hipFuncSetAttribute((const void*)k_gru,
      hipFuncAttributeMaxDynamicSharedMemorySize, WLDS_BYTES);
  k_gru<<<MPAD/128, 512, WLDS_BYTES, stream>>>(AX0, AXL, (const uint32_t*)WfT,
                                               accum, probs);
  k_out<<<(NTR+255)/256, 256, 0, stream>>>(tri, accum, Wo, bo, y, out);
}